// Round 2
// baseline (290.325 us; speedup 1.0000x reference)
//
#include <hip/hip_runtime.h>

// YOLO-v1 style loss on MI355X (gfx950).
// Inputs: d_in[0] = output (BATCH*S*S*30 fp32), d_in[1] = target (same).
// Outputs: d_out[0..2] = (loss, sum_iou, acc) as fp32.
//
// Memory-bound problem: 96.3 MB input -> ~15.3 us HBM floor at 6.3 TB/s.
// R1 was latency-bound (403 GB/s): per-thread 120B-stride scalar loads made
// every vmem instruction touch 64 cache lines. R2 stages tiles through LDS
// with coalesced float4 loads, then reads rows from LDS.

#define NACC 8
#define CELLS 256                 // cells per block (== blockDim.x)
#define TILE_FLOATS (CELLS * 30)  // 7680 floats = 30720 B per array
// ws layout: [0]=n_obj [1]=contain_num [2]=obj_num [3]=notcontain_num
//            [4]=noobj_num [5]=class_num [6]=sum_iou [7]=acc [8]=block ticket

__device__ __forceinline__ float wave_reduce_sum(float v) {
    #pragma unroll
    for (int off = 32; off > 0; off >>= 1)
        v += __shfl_down(v, off, 64);
    return v;
}

__global__ __launch_bounds__(256) void yolo_loss_kernel(
        const float* __restrict__ out,
        const float* __restrict__ tgt,
        float* __restrict__ ws,
        float* __restrict__ res, int N) {
    __shared__ float sA[TILE_FLOATS];   // output tile
    __shared__ float sB[TILE_FLOATS];   // target tile
    __shared__ float sred[4][NACC];

    const int tile0 = blockIdx.x * CELLS;
    const int cells = min(CELLS, N - tile0);
    const size_t base = (size_t)tile0 * 30;

    if (cells == CELLS) {
        // fast path: fully coalesced float4 staging (tile base is 16B-aligned:
        // 30720B per tile)
        const float4* gA = (const float4*)(out + base);
        const float4* gB = (const float4*)(tgt + base);
        float4* lA = (float4*)sA;
        float4* lB = (float4*)sB;
        #pragma unroll
        for (int j = 0; j < 8; j++) {
            const int f = j * 256 + threadIdx.x;
            if (f < TILE_FLOATS / 4) {
                lA[f] = gA[f];
                lB[f] = gB[f];
            }
        }
    } else {
        // tail fallback (never taken for N=401408): scalar staging
        for (int f = threadIdx.x; f < cells * 30; f += 256) {
            sA[f] = out[base + f];
            sB[f] = tgt[base + f];
        }
    }
    __syncthreads();

    float v[NACC];
    #pragma unroll
    for (int k = 0; k < NACC; k++) v[k] = 0.f;

    if ((int)threadIdx.x < cells) {
        // row reads from LDS: 120B rows, 8B-aligned -> ds_read_b64
        float ov[30], tv[30];
        const float2* a2 = (const float2*)(sA + threadIdx.x * 30);
        const float2* b2 = (const float2*)(sB + threadIdx.x * 30);
        #pragma unroll
        for (int k = 0; k < 15; k++) {
            const float2 xa = a2[k];
            const float2 xb = b2[k];
            ov[2 * k] = xa.x; ov[2 * k + 1] = xa.y;
            tv[2 * k] = xb.x; tv[2 * k + 1] = xb.y;
        }

        const float m = (tv[4] > 0.f) ? 1.f : 0.f;

        // target corners (xy/S +- 0.5*wh), matching reference arithmetic
        const float tx0 = tv[0] / 7.f - 0.5f * tv[2];
        const float ty0 = tv[1] / 7.f - 0.5f * tv[3];
        const float tx1 = tv[0] / 7.f + 0.5f * tv[2];
        const float ty1 = tv[1] / 7.f + 0.5f * tv[3];
        const float at  = (tx1 - tx0) * (ty1 - ty0);

        float iou[2];
        #pragma unroll
        for (int b = 0; b < 2; b++) {
            const float* pb = ov + b * 5;
            const float px0 = pb[0] / 7.f - 0.5f * pb[2];
            const float py0 = pb[1] / 7.f - 0.5f * pb[3];
            const float px1 = pb[0] / 7.f + 0.5f * pb[2];
            const float py1 = pb[1] / 7.f + 0.5f * pb[3];
            const float ap  = (px1 - px0) * (py1 - py0);
            const float ulx = fmaxf(px0, tx0), uly = fmaxf(py0, ty0);
            const float lrx = fminf(px1, tx1), lry = fminf(py1, ty1);
            const float wi  = fmaxf(lrx - ulx, 0.f);
            const float hi  = fmaxf(lry - uly, 0.f);
            const float inter = wi * hi;
            iou[b] = inter / (ap + at - inter);
        }

        // argmax with first-max tie-break: resp=1 only if strictly greater
        const int resp = (iou[1] > iou[0]) ? 1 : 0;
        const float max_iou = fmaxf(iou[0], iou[1]);
        const float min_iou = fminf(iou[0], iou[1]);
        const float* rb = ov + resp * 5;
        const float* nb = ov + (1 - resp) * 5;

        {
            const float dx = rb[0] - tv[0];
            const float dy = rb[1] - tv[1];
            const float dw = sqrtf(rb[2]) - sqrtf(tv[2]);
            const float dh = sqrtf(rb[3]) - sqrtf(tv[3]);
            v[1] = m * (dx * dx + dy * dy + dw * dw + dh * dh);
        }
        {
            const float d = rb[4] - max_iou;
            v[2] = m * d * d;
        }
        v[3] = m * nb[4] * nb[4];
        {
            const float d0 = ov[4] - tv[4];
            const float d1 = ov[9] - tv[9];
            v[4] = (1.f - m) * (d0 * d0 + d1 * d1);
        }

        // class loss + argmax accuracy (first-max semantics via strict >)
        float cls_sum = 0.f;
        int oarg = 0, targ = 0;
        float obest = ov[10], tbest = tv[10];
        #pragma unroll
        for (int c = 0; c < 20; c++) {
            const float oc = ov[10 + c], tc = tv[10 + c];
            const float d = oc - tc;
            cls_sum += d * d;
            if (oc > obest) { obest = oc; oarg = c; }
            if (tc > tbest) { tbest = tc; targ = c; }
        }
        v[5] = m * cls_sum;
        v[6] = m * min_iou;
        v[7] = (m > 0.f && oarg == targ) ? 1.f : 0.f;
        v[0] = m;
    }

    // wave reduce -> LDS block reduce -> one atomicAdd set per block
    const int lane = threadIdx.x & 63;
    const int wid  = threadIdx.x >> 6;
    #pragma unroll
    for (int k = 0; k < NACC; k++) v[k] = wave_reduce_sum(v[k]);
    if (lane == 0) {
        #pragma unroll
        for (int k = 0; k < NACC; k++) sred[wid][k] = v[k];
    }
    __syncthreads();

    if (threadIdx.x == 0) {
        #pragma unroll
        for (int k = 0; k < NACC; k++) {
            const float s = sred[0][k] + sred[1][k] + sred[2][k] + sred[3][k];
            atomicAdd(&ws[k], s);
        }
        __threadfence();
        // completion ticket: last block finalizes (saves a dispatch)
        const unsigned old = atomicAdd((unsigned int*)(ws + NACC), 1u);
        if (old == gridDim.x - 1) {
            float acc[NACC];
            #pragma unroll
            for (int k = 0; k < NACC; k++)
                acc[k] = atomicAdd(&ws[k], 0.f);  // coherent read-back
            const float n_obj   = acc[0];
            const float n_noobj = (float)N - n_obj;
            const float contain     = acc[1] / (2.f * n_obj);
            const float obj_loss    = acc[2] / n_obj;
            const float not_contain = acc[3] / n_obj;
            const float noobj_loss  = acc[4] / (2.f * n_noobj);
            const float class_loss  = acc[5] / (n_obj * 20.f);
            res[0] = 5.f * contain + obj_loss
                   + 0.5f * (noobj_loss + not_contain) + class_loss;
            res[1] = acc[6];
            res[2] = acc[7];
        }
    }
}

extern "C" void kernel_launch(void* const* d_in, const int* in_sizes, int n_in,
                              void* d_out, int out_size, void* d_ws, size_t ws_size,
                              hipStream_t stream) {
    const float* out_p = (const float*)d_in[0];
    const float* tgt_p = (const float*)d_in[1];
    float* ws  = (float*)d_ws;
    float* res = (float*)d_out;
    const int N = in_sizes[0] / 30;  // 8192*7*7 = 401408 cells

    hipMemsetAsync(ws, 0, (NACC + 1) * sizeof(float), stream);
    const int grid = (N + CELLS - 1) / CELLS;  // 1568 blocks
    yolo_loss_kernel<<<grid, 256, 0, stream>>>(out_p, tgt_p, ws, res, N);
}

// Round 3
// 123.480 us; speedup vs baseline: 2.3512x; 2.3512x over previous
//
#include <hip/hip_runtime.h>

// YOLO-v1 style loss on MI355X (gfx950).
// Inputs: d_in[0] = output (BATCH*S*S*30 fp32), d_in[1] = target (same).
// Outputs: d_out[0..2] = (loss, sum_iou, acc) as fp32.
//
// R1/R2 post-mortem: both were bound (~175-220us, data-independent) by
// 1568 blocks x 8 atomicAdds to ONE cache line -> serialized L2 RMWs.
// R3: persistent 512-block grid-stride kernel, register accumulation across
// tiles, plain per-block partial stores (no atomics), tiny reduce kernel.

#define NACC 8
#define CELLS 256                 // cells per tile (== blockDim.x)
#define TILE_FLOATS (CELLS * 30)  // 7680 floats = 30720 B per array
#define GRID 512                  // 2 blocks/CU

__device__ __forceinline__ float wave_reduce_sum(float v) {
    #pragma unroll
    for (int off = 32; off > 0; off >>= 1)
        v += __shfl_down(v, off, 64);
    return v;
}

__global__ __launch_bounds__(256) void yolo_loss_kernel(
        const float* __restrict__ out,
        const float* __restrict__ tgt,
        float* __restrict__ partials, int N) {
    __shared__ float sA[TILE_FLOATS];   // output tile
    __shared__ float sB[TILE_FLOATS];   // target tile
    __shared__ float sred[4][NACC];

    const int numTiles = (N + CELLS - 1) / CELLS;

    float v[NACC];
    #pragma unroll
    for (int k = 0; k < NACC; k++) v[k] = 0.f;

    for (int tile = blockIdx.x; tile < numTiles; tile += GRID) {
        const int tile0 = tile * CELLS;
        const int cells = min(CELLS, N - tile0);
        const size_t base = (size_t)tile0 * 30;

        if (cells == CELLS) {
            // coalesced float4 staging (tile base 16B-aligned: 30720B tiles)
            const float4* gA = (const float4*)(out + base);
            const float4* gB = (const float4*)(tgt + base);
            float4* lA = (float4*)sA;
            float4* lB = (float4*)sB;
            #pragma unroll
            for (int j = 0; j < 8; j++) {
                const int f = j * 256 + threadIdx.x;
                if (f < TILE_FLOATS / 4) {
                    lA[f] = gA[f];
                    lB[f] = gB[f];
                }
            }
        } else {
            for (int f = threadIdx.x; f < cells * 30; f += 256) {
                sA[f] = out[base + f];
                sB[f] = tgt[base + f];
            }
        }
        __syncthreads();

        if ((int)threadIdx.x < cells) {
            float ov[30], tv[30];
            const float2* a2 = (const float2*)(sA + threadIdx.x * 30);
            const float2* b2 = (const float2*)(sB + threadIdx.x * 30);
            #pragma unroll
            for (int k = 0; k < 15; k++) {
                const float2 xa = a2[k];
                const float2 xb = b2[k];
                ov[2 * k] = xa.x; ov[2 * k + 1] = xa.y;
                tv[2 * k] = xb.x; tv[2 * k + 1] = xb.y;
            }

            const float m = (tv[4] > 0.f) ? 1.f : 0.f;

            const float tx0 = tv[0] / 7.f - 0.5f * tv[2];
            const float ty0 = tv[1] / 7.f - 0.5f * tv[3];
            const float tx1 = tv[0] / 7.f + 0.5f * tv[2];
            const float ty1 = tv[1] / 7.f + 0.5f * tv[3];
            const float at  = (tx1 - tx0) * (ty1 - ty0);

            float iou[2];
            #pragma unroll
            for (int b = 0; b < 2; b++) {
                const float* pb = ov + b * 5;
                const float px0 = pb[0] / 7.f - 0.5f * pb[2];
                const float py0 = pb[1] / 7.f - 0.5f * pb[3];
                const float px1 = pb[0] / 7.f + 0.5f * pb[2];
                const float py1 = pb[1] / 7.f + 0.5f * pb[3];
                const float ap  = (px1 - px0) * (py1 - py0);
                const float ulx = fmaxf(px0, tx0), uly = fmaxf(py0, ty0);
                const float lrx = fminf(px1, tx1), lry = fminf(py1, ty1);
                const float wi  = fmaxf(lrx - ulx, 0.f);
                const float hi  = fmaxf(lry - uly, 0.f);
                const float inter = wi * hi;
                iou[b] = inter / (ap + at - inter);
            }

            // argmax, first-max tie-break: resp=1 only if strictly greater
            const int resp = (iou[1] > iou[0]) ? 1 : 0;
            const float max_iou = fmaxf(iou[0], iou[1]);
            const float min_iou = fminf(iou[0], iou[1]);
            const float* rb = ov + resp * 5;
            const float* nb = ov + (1 - resp) * 5;

            {
                const float dx = rb[0] - tv[0];
                const float dy = rb[1] - tv[1];
                const float dw = sqrtf(rb[2]) - sqrtf(tv[2]);
                const float dh = sqrtf(rb[3]) - sqrtf(tv[3]);
                v[1] += m * (dx * dx + dy * dy + dw * dw + dh * dh);
            }
            {
                const float d = rb[4] - max_iou;
                v[2] += m * d * d;
            }
            v[3] += m * nb[4] * nb[4];
            {
                const float d0 = ov[4] - tv[4];
                const float d1 = ov[9] - tv[9];
                v[4] += (1.f - m) * (d0 * d0 + d1 * d1);
            }

            float cls_sum = 0.f;
            int oarg = 0, targ = 0;
            float obest = ov[10], tbest = tv[10];
            #pragma unroll
            for (int c = 0; c < 20; c++) {
                const float oc = ov[10 + c], tc = tv[10 + c];
                const float d = oc - tc;
                cls_sum += d * d;
                if (oc > obest) { obest = oc; oarg = c; }
                if (tc > tbest) { tbest = tc; targ = c; }
            }
            v[5] += m * cls_sum;
            v[6] += m * min_iou;
            v[7] += (m > 0.f && oarg == targ) ? 1.f : 0.f;
            v[0] += m;
        }
        __syncthreads();   // protect sA/sB before next tile's staging
    }

    // block reduce 8 sums, then ONE plain store set per block (no atomics)
    const int lane = threadIdx.x & 63;
    const int wid  = threadIdx.x >> 6;
    #pragma unroll
    for (int k = 0; k < NACC; k++) v[k] = wave_reduce_sum(v[k]);
    if (lane == 0) {
        #pragma unroll
        for (int k = 0; k < NACC; k++) sred[wid][k] = v[k];
    }
    __syncthreads();
    if (threadIdx.x < NACC) {
        const int k = threadIdx.x;
        partials[blockIdx.x * NACC + k] =
            sred[0][k] + sred[1][k] + sred[2][k] + sred[3][k];
    }
}

__global__ __launch_bounds__(256) void yolo_finalize_kernel(
        const float* __restrict__ partials,
        float* __restrict__ res, int N) {
    __shared__ float sred[4][NACC];
    float v[NACC];
    #pragma unroll
    for (int k = 0; k < NACC; k++) v[k] = 0.f;
    // 512 partial rows, 256 threads -> 2 rows per thread
    #pragma unroll
    for (int r = 0; r < 2; r++) {
        const int b = r * 256 + threadIdx.x;
        #pragma unroll
        for (int k = 0; k < NACC; k++) v[k] += partials[b * NACC + k];
    }
    const int lane = threadIdx.x & 63;
    const int wid  = threadIdx.x >> 6;
    #pragma unroll
    for (int k = 0; k < NACC; k++) v[k] = wave_reduce_sum(v[k]);
    if (lane == 0) {
        #pragma unroll
        for (int k = 0; k < NACC; k++) sred[wid][k] = v[k];
    }
    __syncthreads();
    if (threadIdx.x == 0) {
        float acc[NACC];
        #pragma unroll
        for (int k = 0; k < NACC; k++)
            acc[k] = sred[0][k] + sred[1][k] + sred[2][k] + sred[3][k];
        const float n_obj   = acc[0];
        const float n_noobj = (float)N - n_obj;
        const float contain     = acc[1] / (2.f * n_obj);
        const float obj_loss    = acc[2] / n_obj;
        const float not_contain = acc[3] / n_obj;
        const float noobj_loss  = acc[4] / (2.f * n_noobj);
        const float class_loss  = acc[5] / (n_obj * 20.f);
        res[0] = 5.f * contain + obj_loss
               + 0.5f * (noobj_loss + not_contain) + class_loss;
        res[1] = acc[6];
        res[2] = acc[7];
    }
}

extern "C" void kernel_launch(void* const* d_in, const int* in_sizes, int n_in,
                              void* d_out, int out_size, void* d_ws, size_t ws_size,
                              hipStream_t stream) {
    const float* out_p = (const float*)d_in[0];
    const float* tgt_p = (const float*)d_in[1];
    float* ws  = (float*)d_ws;   // 512*8 partial sums
    float* res = (float*)d_out;
    const int N = in_sizes[0] / 30;  // 8192*7*7 = 401408 cells

    yolo_loss_kernel<<<GRID, 256, 0, stream>>>(out_p, tgt_p, ws, N);
    yolo_finalize_kernel<<<1, 256, 0, stream>>>(ws, res, N);
}